// Round 1
// baseline (612.114 us; speedup 1.0000x reference)
//
#include <hip/hip_runtime.h>

// Sparse UNet: 2 streams x (3 x [smconv27 -> BN(train) -> ReLU]) -> point gather -> linear head -> per-batch mean.
// Strategy:
//  - conv kernels write PRE-BN output + per-block partial (sum, sumsq) per channel
//  - stats kernel reduces partials -> scale/shift (BN fused as affine into the NEXT gather)
//  - head is linear => only per-batch channel sums of h3 are needed
// Workspace use: ~46.2 MB (p1/p3 reuse one buffer, p2 separate, small stat buffers).

#define DEVI __device__ __forceinline__

constexpr int KNBR = 27;

DEVI float bnr(float x, float sc, float sh) {
    float y = fmaf(x, sc, sh);
    return y > 0.f ? y : 0.f;
}

DEVI void fma4(float4& a, float s, float4 w) {
    a.x = fmaf(s, w.x, a.x);
    a.y = fmaf(s, w.y, a.y);
    a.z = fmaf(s, w.z, a.z);
    a.w = fmaf(s, w.w, a.w);
}

__global__ void zero_kernel(float* bsum, int nb, float* zrow) {
    int t = threadIdx.x;
    if (t < nb) bsum[t] = 0.f;
    if (t < 32) zrow[t] = 0.f;
}

// One thread handles VPT=2 voxels. W staged in LDS; reads are wave-uniform broadcasts.
template<int CIN, int COUT, bool BN>
__global__ __launch_bounds__(256)
void conv_kernel(const float* __restrict__ f0, const float* __restrict__ f1,
                 const int* __restrict__ nb0, const int* __restrict__ nb1,
                 const float* __restrict__ W, const float* __restrict__ ss,
                 float* __restrict__ o0, float* __restrict__ o1,
                 float* __restrict__ partials, const float* __restrict__ zrow,
                 int N, int nblk)
{
    constexpr int VPT = 2;
    const int s = blockIdx.y;
    const float* __restrict__ feats = s ? f1 : f0;
    const int* __restrict__ nbr = s ? nb1 : nb0;
    float* __restrict__ out = s ? o1 : o0;

    __shared__ __align__(16) float wl[KNBR * CIN * COUT];
    __shared__ float sred[4][64];
    for (int i = threadIdx.x; i < KNBR * CIN * COUT; i += 256) wl[i] = W[i];
    __syncthreads();
    const float4* wl4 = (const float4*)wl;

    float sc[BN ? CIN : 1], sh[BN ? CIN : 1];
    if constexpr (BN) {
        const float* ssp = ss + s * 64;
        #pragma unroll
        for (int c = 0; c < CIN; ++c) { sc[c] = ssp[c]; sh[c] = ssp[32 + c]; }
    } else {
        (void)ss;
    }

    const int tid = threadIdx.x;
    int n[VPT];
    bool act[VPT];
    #pragma unroll
    for (int v = 0; v < VPT; ++v) {
        n[v] = blockIdx.x * (256 * VPT) + v * 256 + tid;
        act[v] = n[v] < N;
    }

    float4 acc[VPT][COUT / 4];
    #pragma unroll
    for (int v = 0; v < VPT; ++v)
        #pragma unroll
        for (int d4 = 0; d4 < COUT / 4; ++d4)
            acc[v][d4] = make_float4(0.f, 0.f, 0.f, 0.f);

    // software-pipelined neighbor index (scalar regs, no runtime-indexed array)
    int cidx[VPT];
    #pragma unroll
    for (int v = 0; v < VPT; ++v)
        cidx[v] = act[v] ? nbr[(size_t)n[v] * KNBR] : 0;

    for (int k = 0; k < KNBR; ++k) {
        int kn = (k + 1 < KNBR) ? (k + 1) : (KNBR - 1);
        int nxt[VPT];
        #pragma unroll
        for (int v = 0; v < VPT; ++v)
            nxt[v] = act[v] ? nbr[(size_t)n[v] * KNBR + kn] : 0;

        const float* pv[VPT];
        #pragma unroll
        for (int v = 0; v < VPT; ++v)
            pv[v] = act[v] ? (feats + (size_t)cidx[v] * CIN) : zrow;

        float vin[VPT][CIN];
        #pragma unroll
        for (int v = 0; v < VPT; ++v) {
            if constexpr (CIN % 4 == 0) {
                #pragma unroll
                for (int c4 = 0; c4 < CIN / 4; ++c4) {
                    float4 u = ((const float4*)pv[v])[c4];
                    vin[v][4 * c4 + 0] = u.x;
                    vin[v][4 * c4 + 1] = u.y;
                    vin[v][4 * c4 + 2] = u.z;
                    vin[v][4 * c4 + 3] = u.w;
                }
            } else {
                #pragma unroll
                for (int c2 = 0; c2 < CIN / 2; ++c2) {
                    float2 u = ((const float2*)pv[v])[c2];
                    vin[v][2 * c2 + 0] = u.x;
                    vin[v][2 * c2 + 1] = u.y;
                }
            }
            if constexpr (BN) {
                #pragma unroll
                for (int c = 0; c < CIN; ++c) vin[v][c] = bnr(vin[v][c], sc[c], sh[c]);
            }
        }

        #pragma unroll
        for (int c = 0; c < CIN; ++c) {
            #pragma unroll
            for (int d4 = 0; d4 < COUT / 4; ++d4) {
                float4 w = wl4[(k * CIN + c) * (COUT / 4) + d4];
                #pragma unroll
                for (int v = 0; v < VPT; ++v) fma4(acc[v][d4], vin[v][c], w);
            }
        }

        #pragma unroll
        for (int v = 0; v < VPT; ++v) cidx[v] = nxt[v];
    }

    // store pre-BN output
    #pragma unroll
    for (int v = 0; v < VPT; ++v) {
        if (act[v]) {
            float4* orow = (float4*)(out + (size_t)n[v] * COUT);
            #pragma unroll
            for (int d4 = 0; d4 < COUT / 4; ++d4) orow[d4] = acc[v][d4];
        }
    }

    // BN statistics: per-thread (sum, sumsq) per channel -> wave butterfly -> block -> partials
    float ts[COUT], tq[COUT];
    #pragma unroll
    for (int d4 = 0; d4 < COUT / 4; ++d4) {
        float4 a0 = acc[0][d4];
        float4 a1 = acc[1][d4];
        ts[4 * d4 + 0] = a0.x + a1.x;  tq[4 * d4 + 0] = a0.x * a0.x + a1.x * a1.x;
        ts[4 * d4 + 1] = a0.y + a1.y;  tq[4 * d4 + 1] = a0.y * a0.y + a1.y * a1.y;
        ts[4 * d4 + 2] = a0.z + a1.z;  tq[4 * d4 + 2] = a0.z * a0.z + a1.z * a1.z;
        ts[4 * d4 + 3] = a0.w + a1.w;  tq[4 * d4 + 3] = a0.w * a0.w + a1.w * a1.w;
    }
    #pragma unroll
    for (int d = 0; d < COUT; ++d) {
        #pragma unroll
        for (int m = 32; m >= 1; m >>= 1) {
            ts[d] += __shfl_xor(ts[d], m);
            tq[d] += __shfl_xor(tq[d], m);
        }
    }
    const int lane = tid & 63;
    const int wid = tid >> 6;
    if (lane == 0) {
        #pragma unroll
        for (int d = 0; d < COUT; ++d) {
            sred[wid][d] = ts[d];
            sred[wid][COUT + d] = tq[d];
        }
    }
    __syncthreads();
    if (tid < 2 * COUT) {
        float tot = sred[0][tid] + sred[1][tid] + sred[2][tid] + sred[3][tid];
        partials[((size_t)s * nblk + blockIdx.x) * 64 + tid] = tot;
    }
}

template<int COUT>
__global__ __launch_bounds__(256)
void stats_kernel(const float* __restrict__ partials, int nblk, int N,
                  const float* __restrict__ g, const float* __restrict__ b,
                  float* __restrict__ ss)
{
    const int s = blockIdx.y;
    const int tid = threadIdx.x;
    const float* P = partials + (size_t)s * nblk * 64;
    const int q = tid & 63;
    const int ch = tid >> 6;   // 4 chunks
    float a = 0.f;
    for (int i = ch; i < nblk; i += 4) a += P[(size_t)i * 64 + q];
    __shared__ float red[256];
    red[tid] = a;
    __syncthreads();
    if (tid < 64) red[tid] = red[tid] + red[64 + tid] + red[128 + tid] + red[192 + tid];
    __syncthreads();
    if (tid < COUT) {
        float sum = red[tid];
        float sq = red[COUT + tid];
        float mean = sum / (float)N;
        float var = sq / (float)N - mean * mean;
        float scl = g[tid] * rsqrtf(var + 1e-4f);
        float sft = b[tid] - mean * scl;
        float* ssp = ss + s * 64;
        ssp[tid] = scl;
        ssp[32 + tid] = sft;
    }
}

// Per-batch channel sums of BN3+ReLU(h3) over gathered points.
__global__ __launch_bounds__(256)
void pointsum_kernel(const float* __restrict__ h0, const float* __restrict__ h1,
                     const int* __restrict__ id0, const int* __restrict__ id1,
                     const float* __restrict__ ss, float* __restrict__ bsum,
                     int Ppb, int bpb, int bs)
{
    const int s = blockIdx.y;
    const float* __restrict__ h = s ? h1 : h0;
    const int* __restrict__ ids = s ? id1 : id0;
    const int batch = blockIdx.x / bpb;
    const int blk = blockIdx.x % bpb;

    const float* ssp = ss + s * 64;
    float sc[16], sh[16];
    #pragma unroll
    for (int c = 0; c < 16; ++c) { sc[c] = ssp[c]; sh[c] = ssp[32 + c]; }

    float acc[16];
    #pragma unroll
    for (int c = 0; c < 16; ++c) acc[c] = 0.f;

    const int* bid = ids + (size_t)batch * Ppb;
    const int base = blk * (256 * 8) + threadIdx.x;
    for (int i = 0; i < 8; ++i) {
        int off = base + i * 256;
        if (off < Ppb) {
            int vx = bid[off];
            const float4* r = (const float4*)(h + (size_t)vx * 16);
            #pragma unroll
            for (int c4 = 0; c4 < 4; ++c4) {
                float4 u = r[c4];
                acc[4 * c4 + 0] += bnr(u.x, sc[4 * c4 + 0], sh[4 * c4 + 0]);
                acc[4 * c4 + 1] += bnr(u.y, sc[4 * c4 + 1], sh[4 * c4 + 1]);
                acc[4 * c4 + 2] += bnr(u.z, sc[4 * c4 + 2], sh[4 * c4 + 2]);
                acc[4 * c4 + 3] += bnr(u.w, sc[4 * c4 + 3], sh[4 * c4 + 3]);
            }
        }
    }

    #pragma unroll
    for (int c = 0; c < 16; ++c) {
        #pragma unroll
        for (int m = 32; m >= 1; m >>= 1) acc[c] += __shfl_xor(acc[c], m);
    }
    __shared__ float sred[4][16];
    const int lane = threadIdx.x & 63;
    const int wid = threadIdx.x >> 6;
    if (lane == 0) {
        #pragma unroll
        for (int c = 0; c < 16; ++c) sred[wid][c] = acc[c];
    }
    __syncthreads();
    if (threadIdx.x < 16) {
        float tot = sred[0][threadIdx.x] + sred[1][threadIdx.x] + sred[2][threadIdx.x] + sred[3][threadIdx.x];
        atomicAdd(&bsum[((size_t)s * bs + batch) * 16 + threadIdx.x], tot);
    }
}

// out[r][b][x]: r0=green stream0, r1=green stream1, r2=red stream0, r3=red stream1
__global__ void final_kernel(const float* __restrict__ bsum,
                             const float* __restrict__ Wg, const float* __restrict__ bg,
                             const float* __restrict__ Wr, const float* __restrict__ br,
                             float* __restrict__ out, int bs, float invP)
{
    const int t = threadIdx.x;
    const int total = 4 * bs * 3;
    if (t < total) {
        const int x = t % 3;
        const int b = (t / 3) % bs;
        const int r = t / (3 * bs);
        const int s = r & 1;
        const float* W = (r < 2) ? Wg : Wr;
        const float* bias = (r < 2) ? bg : br;
        const float* m = bsum + ((size_t)s * bs + b) * 16;
        float a = bias[x];
        #pragma unroll
        for (int c = 0; c < 16; ++c) a = fmaf(m[c] * invP, W[c * 3 + x], a);
        out[t] = a;
    }
}

extern "C" void kernel_launch(void* const* d_in, const int* in_sizes, int n_in,
                              void* d_out, int out_size, void* d_ws, size_t ws_size,
                              hipStream_t stream)
{
    (void)n_in; (void)ws_size;
    const float* vf0 = (const float*)d_in[0];
    const int*   nb0 = (const int*)d_in[1];
    const int*   id0 = (const int*)d_in[2];
    const float* vf1 = (const float*)d_in[3];
    const int*   nb1 = (const int*)d_in[4];
    const int*   id1 = (const int*)d_in[5];
    // d_in[6] = bs (device scalar) -- derived from out_size instead
    const float* W1 = (const float*)d_in[7];
    const float* g1 = (const float*)d_in[8];
    const float* b1 = (const float*)d_in[9];
    const float* W2 = (const float*)d_in[10];
    const float* g2 = (const float*)d_in[11];
    const float* b2 = (const float*)d_in[12];
    const float* W3 = (const float*)d_in[13];
    const float* g3 = (const float*)d_in[14];
    const float* b3 = (const float*)d_in[15];
    const float* Wg = (const float*)d_in[16];
    const float* bg = (const float*)d_in[17];
    const float* Wr = (const float*)d_in[18];
    const float* br = (const float*)d_in[19];

    const int N = in_sizes[0] / 6;       // 120000
    const int npts = in_sizes[2];        // bs * P
    const int bs = out_size / 12;        // out = [4, bs, 3]
    const int Ppb = npts / bs;           // points per batch

    const int nblk = (N + 511) / 512;    // 256 threads x VPT=2

    float* ws = (float*)d_ws;
    float* p1 = ws;                                    // 2 * N * 16 (reused for h3)
    float* p2 = p1 + 2 * (size_t)N * 16;               // 2 * N * 32
    float* partials = p2 + 2 * (size_t)N * 32;         // 2 * nblk * 64
    float* ssb = partials + 2 * (size_t)nblk * 64;     // [2][2][32]
    float* bsum = ssb + 128;                           // [2][bs][16]
    float* zrow = bsum + 2 * (size_t)bs * 16;          // 32 zeros (dummy row)

    zero_kernel<<<1, 256, 0, stream>>>(bsum, 2 * bs * 16, zrow);

    dim3 cg(nblk, 2);
    conv_kernel<6, 16, false><<<cg, 256, 0, stream>>>(
        vf0, vf1, nb0, nb1, W1, ssb, p1, p1 + (size_t)N * 16, partials, zrow, N, nblk);
    stats_kernel<16><<<dim3(1, 2), 256, 0, stream>>>(partials, nblk, N, g1, b1, ssb);

    conv_kernel<16, 32, true><<<cg, 256, 0, stream>>>(
        p1, p1 + (size_t)N * 16, nb0, nb1, W2, ssb, p2, p2 + (size_t)N * 32, partials, zrow, N, nblk);
    stats_kernel<32><<<dim3(1, 2), 256, 0, stream>>>(partials, nblk, N, g2, b2, ssb);

    conv_kernel<32, 16, true><<<cg, 256, 0, stream>>>(
        p2, p2 + (size_t)N * 32, nb0, nb1, W3, ssb, p1, p1 + (size_t)N * 16, partials, zrow, N, nblk);
    stats_kernel<16><<<dim3(1, 2), 256, 0, stream>>>(partials, nblk, N, g3, b3, ssb);

    const int bpb = (Ppb + 2047) / 2048;
    pointsum_kernel<<<dim3(bpb * bs, 2), 256, 0, stream>>>(
        p1, p1 + (size_t)N * 16, id0, id1, ssb, bsum, Ppb, bpb, bs);
    final_kernel<<<1, 64, 0, stream>>>(bsum, Wg, bg, Wr, br, (float*)d_out, bs, 1.0f / Ppb);
}